// Round 3
// baseline (783.084 us; speedup 1.0000x reference)
//
#include <hip/hip_runtime.h>
#include <hip/hip_bf16.h>

#define NN 200000
#define D 64
#define NB_EDGE 800        // edge-pass blocks; group g = blockIdx & 7

// ---------------- utility zero kernels ----------------
__global__ __launch_bounds__(256) void zero_f4(float4* __restrict__ p, int n4) {
    int i = blockIdx.x * blockDim.x + threadIdx.x;
    if (i < n4) p[i] = make_float4(0.f, 0.f, 0.f, 0.f);
}
__global__ __launch_bounds__(256) void zero_i(int* __restrict__ p, int n) {
    int i = blockIdx.x * blockDim.x + threadIdx.x;
    if (i < n) p[i] = 0;
}

// ---------------- grouped CSR build ----------------
// Edge e handled by block b -> group g = b & gmask. Counters cnt[g*NN + r] are
// only touched by blocks of one XCD (blockIdx%8 round-robin) -> L2-local atomics.
__global__ __launch_bounds__(256) void count_g(const int* __restrict__ rows,
                                               int* __restrict__ cnt,
                                               int E, int epb, int gmask) {
    int b = blockIdx.x;
    int g = b & gmask;
    int start = b * epb;
    int end   = min(E, start + epb);
    int* cg = cnt + (size_t)g * NN;
    for (int e = start + threadIdx.x; e < end; e += 256)
        atomicAdd(&cg[rows[e]], 1);
}

__global__ __launch_bounds__(256) void scatter_g(const int* __restrict__ rows,
                                                 const int* __restrict__ cols,
                                                 const float* __restrict__ vals,
                                                 int* __restrict__ cursor,
                                                 int2* __restrict__ packed,
                                                 int E, int epb, int gmask) {
    int b = blockIdx.x;
    int g = b & gmask;
    int start = b * epb;
    int end   = min(E, start + epb);
    int* cg = cursor + (size_t)g * NN;
    for (int e = start + threadIdx.x; e < end; e += 256) {
        int pos = atomicAdd(&cg[rows[e]], 1);
        packed[pos] = make_int2(cols[e], __float_as_int(vals[e]));
    }
}

// ---------------- scan over M = G*NN counters -> exclusive row_ptr ----------------
__global__ __launch_bounds__(1024) void scan1(const int* __restrict__ cnt,
                                              int* __restrict__ rp,
                                              int* __restrict__ totals, int M) {
    __shared__ int s[1024];
    int t = threadIdx.x;
    int i = blockIdx.x * 1024 + t;
    int v = (i < M) ? cnt[i] : 0;
    s[t] = v;
    __syncthreads();
    #pragma unroll
    for (int off = 1; off < 1024; off <<= 1) {
        int add = (t >= off) ? s[t - off] : 0;
        __syncthreads();
        s[t] += add;
        __syncthreads();
    }
    if (i < M) rp[i] = s[t] - v;               // exclusive within block
    if (t == 1023) totals[blockIdx.x] = s[t];  // block total
}

// single block, exclusive scan of nb block-totals (nb <= 2048); sets rp[M] = E
__global__ __launch_bounds__(1024) void scan2(int* __restrict__ totals, int nb,
                                              int* __restrict__ rp, int M, int E) {
    __shared__ int s[1024];
    __shared__ int carry;
    int t = threadIdx.x;
    if (t == 0) { carry = 0; rp[M] = E; }
    __syncthreads();
    for (int base = 0; base < nb; base += 1024) {
        int i = base + t;
        int v = (i < nb) ? totals[i] : 0;
        s[t] = v;
        __syncthreads();
        #pragma unroll
        for (int off = 1; off < 1024; off <<= 1) {
            int add = (t >= off) ? s[t - off] : 0;
            __syncthreads();
            s[t] += add;
            __syncthreads();
        }
        if (i < nb) totals[i] = carry + s[t] - v;   // exclusive across all
        __syncthreads();
        if (t == 0) carry += s[1023];
        __syncthreads();
    }
}

__global__ __launch_bounds__(1024) void scan3(int* __restrict__ rp,
                                              const int* __restrict__ totals,
                                              int* __restrict__ cursor, int M) {
    int i = blockIdx.x * 1024 + threadIdx.x;
    if (i >= M) return;
    int v = rp[i] + totals[blockIdx.x];
    rp[i] = v;
    cursor[i] = v;
}

// ---------------- gather SpMM over grouped CSR: one wave per row ----------------
template <int G>
__global__ __launch_bounds__(256) void spmm_csr(const int* __restrict__ rp,
                                                const int2* __restrict__ packed,
                                                const float* __restrict__ ein,
                                                float* __restrict__ eout, int n) {
    int wid  = (blockIdx.x * 256 + threadIdx.x) >> 6;
    int lane = threadIdx.x & 63;
    if (wid >= n) return;

    // fetch the 2G segment boundaries with 2G lanes, broadcast to registers
    int v = 0;
    if (lane < 2 * G) {
        int g = (lane < G) ? lane : lane - G;
        v = rp[(size_t)g * n + wid + ((lane < G) ? 0 : 1)];
    }
    int sg[G], cum[G + 1];
    cum[0] = 0;
    #pragma unroll
    for (int g = 0; g < G; ++g) {
        sg[g] = __shfl(v, g);
        int eg = __shfl(v, G + g);
        cum[g + 1] = cum[g] + (eg - sg[g]);
    }
    int T = cum[G];

    float acc = 0.f;
    for (int j0 = 0; j0 < T; j0 += 64) {
        int j = j0 + lane;
        int2 ev = make_int2(0, 0);
        if (j < T) {
            int addr = sg[0] + j;
            #pragma unroll
            for (int g = 1; g < G; ++g)
                if (j >= cum[g]) addr = sg[g] + (j - cum[g]);
            ev = packed[addr];
        }
        int cnt = T - j0; if (cnt > 64) cnt = 64;
        int k = 0;
        for (; k + 4 <= cnt; k += 4) {
            int   c0 = __shfl(ev.x, k),     c1 = __shfl(ev.x, k + 1);
            int   c2 = __shfl(ev.x, k + 2), c3 = __shfl(ev.x, k + 3);
            float v0 = __int_as_float(__shfl(ev.y, k));
            float v1 = __int_as_float(__shfl(ev.y, k + 1));
            float v2 = __int_as_float(__shfl(ev.y, k + 2));
            float v3 = __int_as_float(__shfl(ev.y, k + 3));
            float x0 = ein[c0 * D + lane];
            float x1 = ein[c1 * D + lane];
            float x2 = ein[c2 * D + lane];
            float x3 = ein[c3 * D + lane];
            acc += v0 * x0; acc += v1 * x1; acc += v2 * x2; acc += v3 * x3;
        }
        for (; k < cnt; ++k) {
            int   c = __shfl(ev.x, k);
            float vv = __int_as_float(__shfl(ev.y, k));
            acc += vv * ein[c * D + lane];
        }
    }
    eout[(size_t)wid * D + lane] = acc;
}

// ---------------- fallback scatter SpMM (atomic path) ----------------
__global__ __launch_bounds__(256) void spmm_scatter(const int* __restrict__ rows,
                                                    const int* __restrict__ cols,
                                                    const float* __restrict__ vals,
                                                    const float* __restrict__ ein,
                                                    float* __restrict__ eout, int E) {
    int gid  = blockIdx.x * blockDim.x + threadIdx.x;
    int wid  = gid >> 6;
    int lane = threadIdx.x & 63;
    int nw   = (gridDim.x * blockDim.x) >> 6;
    for (int e = wid; e < E; e += nw) {
        int   r = rows[e];
        int   c = cols[e];
        float v = vals[e];
        float x = ein[(size_t)c * D + lane];
        unsafeAtomicAdd(&eout[(size_t)r * D + lane], v * x);
    }
}

// ---------------- fused 2-layer residual MLP + LayerNorm, in-place ----------------
__global__ __launch_bounds__(256) void mlp_ln_kernel(float* __restrict__ e,
                                                     const float* __restrict__ Ws,
                                                     const float* __restrict__ bs,
                                                     const float* __restrict__ gamma,
                                                     const float* __restrict__ beta) {
    __shared__ float W[2][D][68];
    __shared__ float bsh[2][D];
    __shared__ float gsh[D];
    __shared__ float bet[D];
    __shared__ float X[4][D];

    int t = threadIdx.x;
    for (int i = t; i < 2 * D * D; i += 256) {
        int l = i >> 12;
        int r = (i >> 6) & 63;
        int c = i & 63;
        W[l][r][c] = Ws[i];
    }
    if (t < 128) bsh[t >> 6][t & 63] = bs[t];
    if (t < 64) { gsh[t] = gamma[t]; bet[t] = beta[t]; }
    __syncthreads();

    int wave = t >> 6;
    int lane = t & 63;
    int gwave  = blockIdx.x * 4 + wave;
    int nwaves = gridDim.x * 4;
    float* Xw = X[wave];

    for (int row = gwave; row < NN; row += nwaves) {
        float x = e[(size_t)row * D + lane];
        #pragma unroll
        for (int l = 0; l < 2; ++l) {
            Xw[lane] = x;
            float acc = bsh[l][lane];
            #pragma unroll
            for (int k4 = 0; k4 < 16; ++k4) {
                float4 w  = *(const float4*)&W[l][lane][k4 * 4];
                float4 xv = *(const float4*)&Xw[k4 * 4];
                acc += w.x * xv.x + w.y * xv.y + w.z * xv.z + w.w * xv.w;
            }
            x = fmaxf(acc, 0.f) + x;
        }
        float s = x;
        #pragma unroll
        for (int off = 32; off; off >>= 1) s += __shfl_xor(s, off);
        float mu = s * (1.f / 64.f);
        float xc = x - mu;
        float v2 = xc * xc;
        #pragma unroll
        for (int off = 32; off; off >>= 1) v2 += __shfl_xor(v2, off);
        float var = v2 * (1.f / 64.f);
        e[(size_t)row * D + lane] = xc * rsqrtf(var + 1e-5f) * gsh[lane] + bet[lane];
    }
}

static void run_csr_path(int G, const int* rows, const int* cols, const float* vals,
                         const float* ini, float* out, char* w, int E,
                         hipStream_t stream) {
    size_t e1_b     = (size_t)NN * D * 4;
    size_t packed_b = (size_t)E * 8;
    int    M        = G * NN;
    size_t rp_b     = (((size_t)M + 1) * 4 + 15) & ~(size_t)15;
    size_t cnt_b    = (((size_t)M) * 4 + 15) & ~(size_t)15;

    float* e1     = (float*)w;            w += e1_b;
    int2*  packed = (int2*)w;             w += packed_b;
    int*   rp     = (int*)w;              w += rp_b;
    int*   cnt    = (int*)w;              w += cnt_b;   // doubles as cursor
    int*   totals = (int*)w;

    int epb = (E + NB_EDGE - 1) / NB_EDGE;
    int gmask = G - 1;
    int nb_scan = (M + 1023) / 1024;

    zero_i<<<(M + 255) / 256, 256, 0, stream>>>(cnt, M);
    count_g<<<NB_EDGE, 256, 0, stream>>>(rows, cnt, E, epb, gmask);
    scan1<<<nb_scan, 1024, 0, stream>>>(cnt, rp, totals, M);
    scan2<<<1, 1024, 0, stream>>>(totals, nb_scan, rp, M, E);
    scan3<<<nb_scan, 1024, 0, stream>>>(rp, totals, cnt, M);
    scatter_g<<<NB_EDGE, 256, 0, stream>>>(rows, cols, vals, cnt, packed, E, epb, gmask);

    int spmm_blocks = (NN * 64 + 255) / 256;
    if (G == 8) {
        spmm_csr<8><<<spmm_blocks, 256, 0, stream>>>(rp, packed, ini, e1, NN);
        spmm_csr<8><<<spmm_blocks, 256, 0, stream>>>(rp, packed, e1, out, NN);
    } else {
        spmm_csr<1><<<spmm_blocks, 256, 0, stream>>>(rp, packed, ini, e1, NN);
        spmm_csr<1><<<spmm_blocks, 256, 0, stream>>>(rp, packed, e1, out, NN);
    }
}

extern "C" void kernel_launch(void* const* d_in, const int* in_sizes, int n_in,
                              void* d_out, int out_size, void* d_ws, size_t ws_size,
                              hipStream_t stream) {
    const int*   rows  = (const int*)d_in[0];
    const int*   cols  = (const int*)d_in[1];
    const float* vals  = (const float*)d_in[2];
    const float* ini   = (const float*)d_in[3];
    const float* Ws    = (const float*)d_in[4];
    const float* bs    = (const float*)d_in[5];
    const float* gamma = (const float*)d_in[6];
    const float* beta  = (const float*)d_in[7];
    float* out = (float*)d_out;
    int E = in_sizes[0];

    size_t e1_b     = (size_t)NN * D * 4;
    size_t packed_b = (size_t)E * 8;
    auto need = [&](int G) {
        int M = G * NN;
        return e1_b + packed_b + ((((size_t)M + 1) * 4 + 15) & ~(size_t)15)
             + ((((size_t)M) * 4 + 15) & ~(size_t)15) + 16384;
    };

    if (ws_size >= need(8)) {
        run_csr_path(8, rows, cols, vals, ini, out, (char*)d_ws, E, stream);
    } else if (ws_size >= need(1)) {
        run_csr_path(1, rows, cols, vals, ini, out, (char*)d_ws, E, stream);
    } else {
        float* e1 = (float*)d_ws;
        int n4 = out_size / 4;
        int zb = (n4 + 255) / 256;
        zero_f4<<<zb, 256, 0, stream>>>((float4*)e1,  n4);
        zero_f4<<<zb, 256, 0, stream>>>((float4*)out, n4);
        spmm_scatter<<<12800, 256, 0, stream>>>(rows, cols, vals, ini, e1, E);
        spmm_scatter<<<12800, 256, 0, stream>>>(rows, cols, vals, e1, out, E);
    }

    mlp_ln_kernel<<<2048, 256, 0, stream>>>(out, Ws, bs, gamma, beta);
}

// Round 4
// 461.406 us; speedup vs baseline: 1.6972x; 1.6972x over previous
//
#include <hip/hip_runtime.h>
#include <hip/hip_bf16.h>

#define NN      200000
#define D       64
#define BKT_SH  7            // 128 rows per bucket
#define BKT_RW  128
#define NBKT    1563         // ceil(NN / 128)
#define NCHUNK  256          // edge-pass blocks
#define L2CAP   7936         // max edges per bucket staged in LDS (62 KB)

// ---------------- utility zero kernels ----------------
__global__ __launch_bounds__(256) void zero_f4(float4* __restrict__ p, int n4) {
    int i = blockIdx.x * blockDim.x + threadIdx.x;
    if (i < n4) p[i] = make_float4(0.f, 0.f, 0.f, 0.f);
}
__global__ __launch_bounds__(256) void zero_i(int* __restrict__ p, int n) {
    int i = blockIdx.x * blockDim.x + threadIdx.x;
    if (i < n) p[i] = 0;
}

// ---------------- pass 1: bucket totals (LDS-aggregated) ----------------
__global__ __launch_bounds__(256) void bkt_count(const int* __restrict__ rows,
                                                 int* __restrict__ bkt_total,
                                                 int E, int epb) {
    __shared__ int h[NBKT];
    for (int i = threadIdx.x; i < NBKT; i += 256) h[i] = 0;
    __syncthreads();
    int start = blockIdx.x * epb;
    int end   = min(E, start + epb);
    for (int e = start + threadIdx.x; e < end; e += 256)
        atomicAdd(&h[rows[e] >> BKT_SH], 1);
    __syncthreads();
    for (int i = threadIdx.x; i < NBKT; i += 256)
        if (h[i]) atomicAdd(&bkt_total[i], h[i]);
}

// ---------------- pass 2: single-block exclusive scan over buckets ----------------
__global__ __launch_bounds__(1024) void bkt_scan(const int* __restrict__ bkt_total,
                                                 int* __restrict__ bktstart,
                                                 int* __restrict__ cursor,
                                                 int* __restrict__ rp, int E) {
    __shared__ int s[1024];
    __shared__ int carry;
    int t = threadIdx.x;
    if (t == 0) { carry = 0; bktstart[NBKT] = E; rp[NN] = E; }
    __syncthreads();
    for (int base = 0; base < NBKT; base += 1024) {
        int i = base + t;
        int v = (i < NBKT) ? bkt_total[i] : 0;
        s[t] = v;
        __syncthreads();
        #pragma unroll
        for (int d = 1; d < 1024; d <<= 1) {
            int a = (t >= d) ? s[t - d] : 0;
            __syncthreads();
            s[t] += a;
            __syncthreads();
        }
        if (i < NBKT) { int ex = carry + s[t] - v; bktstart[i] = ex; cursor[i] = ex; }
        __syncthreads();
        if (t == 0) carry += s[1023];
        __syncthreads();
    }
}

// ---------------- pass 3: scatter into bucket-ordered runs ----------------
// Each block reserves one contiguous run per bucket (single atomicAdd), then
// writes its edges into the run -> every line written by exactly one block.
__global__ __launch_bounds__(256) void scatter_l1(const int* __restrict__ rows,
                                                  const int* __restrict__ cols,
                                                  const float* __restrict__ vals,
                                                  int* __restrict__ cursor,
                                                  int2* __restrict__ packed,
                                                  int E, int epb) {
    __shared__ int h[NBKT];
    __shared__ int base[NBKT];
    for (int i = threadIdx.x; i < NBKT; i += 256) h[i] = 0;
    __syncthreads();
    int start = blockIdx.x * epb;
    int end   = min(E, start + epb);
    for (int e = start + threadIdx.x; e < end; e += 256)
        atomicAdd(&h[rows[e] >> BKT_SH], 1);
    __syncthreads();
    for (int i = threadIdx.x; i < NBKT; i += 256) {
        int c = h[i];
        base[i] = c ? atomicAdd(&cursor[i], c) : 0;
        h[i] = 0;                                   // reuse as run cursor
    }
    __syncthreads();
    for (int e = start + threadIdx.x; e < end; e += 256) {
        int r = rows[e];
        int b = r >> BKT_SH;
        int p = base[b] + atomicAdd(&h[b], 1);
        packed[p] = make_int2(cols[e] | ((r & (BKT_RW - 1)) << 18),
                              __float_as_int(vals[e]));
    }
}

// ---------------- pass 4: per-bucket in-place sort to exact CSR (LDS-staged) ----------------
__global__ __launch_bounds__(256) void sort_l2(const int* __restrict__ bktstart,
                                               int2* __restrict__ packed,
                                               int* __restrict__ rp) {
    __shared__ int2 sm[L2CAP];
    __shared__ int  cnt[BKT_RW];
    __shared__ int  cur[BKT_RW];
    int b = blockIdx.x;
    int s = bktstart[b];
    int e = bktstart[b + 1];
    int n = e - s;
    int t = threadIdx.x;
    if (t < BKT_RW) cnt[t] = 0;
    __syncthreads();
    for (int i = t; i < n; i += 256) {
        int2 v = packed[s + i];
        sm[i] = v;
        atomicAdd(&cnt[(v.x >> 18) & (BKT_RW - 1)], 1);
    }
    __syncthreads();
    #pragma unroll
    for (int d = 1; d < BKT_RW; d <<= 1) {       // inclusive scan over 128
        int a = (t < BKT_RW && t >= d) ? cnt[t - d] : 0;
        __syncthreads();
        if (t < BKT_RW) cnt[t] += a;
        __syncthreads();
    }
    if (t < BKT_RW) {
        int ex = t ? cnt[t - 1] : 0;
        cur[t] = ex;
        int g = (b << BKT_SH) + t;
        if (g < NN) rp[g] = s + ex;
    }
    __syncthreads();
    for (int i = t; i < n; i += 256) {
        int2 v = sm[i];
        int  p = atomicAdd(&cur[(v.x >> 18) & (BKT_RW - 1)], 1);
        packed[s + p] = make_int2(v.x & 0x3FFFF, v.y);
    }
}

// ---------------- gather SpMM: one wave per row, lane = feature ----------------
__global__ __launch_bounds__(256) void spmm_csr(const int* __restrict__ rp,
                                                const int2* __restrict__ packed,
                                                const float* __restrict__ ein,
                                                float* __restrict__ eout, int n) {
    int wid  = (blockIdx.x * 256 + threadIdx.x) >> 6;
    int lane = threadIdx.x & 63;
    if (wid >= n) return;
    int start = rp[wid];
    int end   = rp[wid + 1];
    float acc = 0.f;
    for (int b0 = start; b0 < end; b0 += 64) {
        int cnt = end - b0; if (cnt > 64) cnt = 64;
        int2 ev = make_int2(0, 0);
        if (lane < cnt) ev = packed[b0 + lane];
        int k = 0;
        for (; k + 4 <= cnt; k += 4) {
            int   c0 = __shfl(ev.x, k),     c1 = __shfl(ev.x, k + 1);
            int   c2 = __shfl(ev.x, k + 2), c3 = __shfl(ev.x, k + 3);
            float v0 = __int_as_float(__shfl(ev.y, k));
            float v1 = __int_as_float(__shfl(ev.y, k + 1));
            float v2 = __int_as_float(__shfl(ev.y, k + 2));
            float v3 = __int_as_float(__shfl(ev.y, k + 3));
            float x0 = ein[c0 * D + lane];
            float x1 = ein[c1 * D + lane];
            float x2 = ein[c2 * D + lane];
            float x3 = ein[c3 * D + lane];
            acc += v0 * x0; acc += v1 * x1; acc += v2 * x2; acc += v3 * x3;
        }
        for (; k < cnt; ++k) {
            int   c = __shfl(ev.x, k);
            float vv = __int_as_float(__shfl(ev.y, k));
            acc += vv * ein[c * D + lane];
        }
    }
    eout[(size_t)wid * D + lane] = acc;
}

// ---------------- fallback scatter SpMM (atomic path) ----------------
__global__ __launch_bounds__(256) void spmm_scatter(const int* __restrict__ rows,
                                                    const int* __restrict__ cols,
                                                    const float* __restrict__ vals,
                                                    const float* __restrict__ ein,
                                                    float* __restrict__ eout, int E) {
    int gid  = blockIdx.x * blockDim.x + threadIdx.x;
    int wid  = gid >> 6;
    int lane = threadIdx.x & 63;
    int nw   = (gridDim.x * blockDim.x) >> 6;
    for (int e = wid; e < E; e += nw) {
        int   r = rows[e];
        int   c = cols[e];
        float v = vals[e];
        float x = ein[(size_t)c * D + lane];
        unsafeAtomicAdd(&eout[(size_t)r * D + lane], v * x);
    }
}

// ---------------- fused 2-layer residual MLP + LayerNorm, in-place ----------------
__global__ __launch_bounds__(256) void mlp_ln_kernel(float* __restrict__ e,
                                                     const float* __restrict__ Ws,
                                                     const float* __restrict__ bs,
                                                     const float* __restrict__ gamma,
                                                     const float* __restrict__ beta) {
    __shared__ float W[2][D][68];
    __shared__ float bsh[2][D];
    __shared__ float gsh[D];
    __shared__ float bet[D];
    __shared__ float X[4][D];

    int t = threadIdx.x;
    for (int i = t; i < 2 * D * D; i += 256) {
        int l = i >> 12;
        int r = (i >> 6) & 63;
        int c = i & 63;
        W[l][r][c] = Ws[i];
    }
    if (t < 128) bsh[t >> 6][t & 63] = bs[t];
    if (t < 64) { gsh[t] = gamma[t]; bet[t] = beta[t]; }
    __syncthreads();

    int wave = t >> 6;
    int lane = t & 63;
    int gwave  = blockIdx.x * 4 + wave;
    int nwaves = gridDim.x * 4;
    float* Xw = X[wave];

    for (int row = gwave; row < NN; row += nwaves) {
        float x = e[(size_t)row * D + lane];
        #pragma unroll
        for (int l = 0; l < 2; ++l) {
            Xw[lane] = x;
            float acc = bsh[l][lane];
            #pragma unroll
            for (int k4 = 0; k4 < 16; ++k4) {
                float4 w  = *(const float4*)&W[l][lane][k4 * 4];
                float4 xv = *(const float4*)&Xw[k4 * 4];
                acc += w.x * xv.x + w.y * xv.y + w.z * xv.z + w.w * xv.w;
            }
            x = fmaxf(acc, 0.f) + x;
        }
        float s = x;
        #pragma unroll
        for (int off = 32; off; off >>= 1) s += __shfl_xor(s, off);
        float mu = s * (1.f / 64.f);
        float xc = x - mu;
        float v2 = xc * xc;
        #pragma unroll
        for (int off = 32; off; off >>= 1) v2 += __shfl_xor(v2, off);
        float var = v2 * (1.f / 64.f);
        e[(size_t)row * D + lane] = xc * rsqrtf(var + 1e-5f) * gsh[lane] + bet[lane];
    }
}

extern "C" void kernel_launch(void* const* d_in, const int* in_sizes, int n_in,
                              void* d_out, int out_size, void* d_ws, size_t ws_size,
                              hipStream_t stream) {
    const int*   rows  = (const int*)d_in[0];
    const int*   cols  = (const int*)d_in[1];
    const float* vals  = (const float*)d_in[2];
    const float* ini   = (const float*)d_in[3];
    const float* Ws    = (const float*)d_in[4];
    const float* bs    = (const float*)d_in[5];
    const float* gamma = (const float*)d_in[6];
    const float* beta  = (const float*)d_in[7];
    float* out = (float*)d_out;
    int E = in_sizes[0];

    // ---- workspace layout ----
    size_t e1_b     = (size_t)NN * D * 4;                         // 51.2 MB
    size_t packed_b = ((size_t)E * 8 + 63) & ~(size_t)63;         // 25.6 MB
    size_t rp_b     = (((size_t)NN + 1) * 4 + 63) & ~(size_t)63;
    size_t bs_b     = (((size_t)NBKT + 1) * 4 + 63) & ~(size_t)63;
    size_t tot_b    = bs_b;
    size_t cur_b    = bs_b;
    size_t need     = e1_b + packed_b + rp_b + bs_b + tot_b + cur_b;

    if (ws_size >= need) {
        char* w = (char*)d_ws;
        float* e1       = (float*)w;   w += e1_b;
        int2*  packed   = (int2*)w;    w += packed_b;
        int*   rp       = (int*)w;     w += rp_b;
        int*   bktstart = (int*)w;     w += bs_b;
        int*   bkt_tot  = (int*)w;     w += tot_b;
        int*   cursor   = (int*)w;

        int epb = (E + NCHUNK - 1) / NCHUNK;
        zero_i<<<(NBKT + 255) / 256, 256, 0, stream>>>(bkt_tot, NBKT);
        bkt_count<<<NCHUNK, 256, 0, stream>>>(rows, bkt_tot, E, epb);
        bkt_scan<<<1, 1024, 0, stream>>>(bkt_tot, bktstart, cursor, rp, E);
        scatter_l1<<<NCHUNK, 256, 0, stream>>>(rows, cols, vals, cursor, packed, E, epb);
        sort_l2<<<NBKT, 256, 0, stream>>>(bktstart, packed, rp);

        int spmm_blocks = (NN * 64 + 255) / 256;
        spmm_csr<<<spmm_blocks, 256, 0, stream>>>(rp, packed, ini, e1, NN);
        spmm_csr<<<spmm_blocks, 256, 0, stream>>>(rp, packed, e1, out, NN);
    } else {
        float* e1 = (float*)d_ws;
        int n4 = out_size / 4;
        int zb = (n4 + 255) / 256;
        zero_f4<<<zb, 256, 0, stream>>>((float4*)e1,  n4);
        zero_f4<<<zb, 256, 0, stream>>>((float4*)out, n4);
        spmm_scatter<<<12800, 256, 0, stream>>>(rows, cols, vals, ini, e1, E);
        spmm_scatter<<<12800, 256, 0, stream>>>(rows, cols, vals, e1, out, E);
    }

    mlp_ln_kernel<<<2048, 256, 0, stream>>>(out, Ws, bs, gamma, beta);
}

// Round 5
// 372.588 us; speedup vs baseline: 2.1017x; 1.2384x over previous
//
#include <hip/hip_runtime.h>
#include <hip/hip_bf16.h>

#define NN      200000
#define D       64
#define NTILE   12500        // NN / 16
#define BKT_SH  7            // 128 rows per bucket
#define BKT_RW  128
#define NBKT    1563         // ceil(NN / 128)
#define NCHUNK  256          // edge-pass blocks
#define L2CAP   7936         // max edges per bucket staged in LDS (62 KB)

typedef __attribute__((ext_vector_type(8))) short short8;
typedef __attribute__((ext_vector_type(4))) float f32x4;

__device__ inline unsigned short f32_to_bf16_rne(float x) {
    unsigned u = __float_as_uint(x);
    unsigned r = u + 0x7FFFu + ((u >> 16) & 1u);
    return (unsigned short)(r >> 16);
}
__device__ inline float bf16_bits_to_f32(unsigned short h) {
    return __uint_as_float(((unsigned)h) << 16);
}

// ---------------- utility zero kernels ----------------
__global__ __launch_bounds__(256) void zero_f4(float4* __restrict__ p, int n4) {
    int i = blockIdx.x * blockDim.x + threadIdx.x;
    if (i < n4) p[i] = make_float4(0.f, 0.f, 0.f, 0.f);
}
__global__ __launch_bounds__(256) void zero_i(int* __restrict__ p, int n) {
    int i = blockIdx.x * blockDim.x + threadIdx.x;
    if (i < n) p[i] = 0;
}

// ---------------- pass 1: bucket totals (LDS-aggregated) ----------------
__global__ __launch_bounds__(256) void bkt_count(const int* __restrict__ rows,
                                                 int* __restrict__ bkt_total,
                                                 int E, int epb) {
    __shared__ int h[NBKT];
    for (int i = threadIdx.x; i < NBKT; i += 256) h[i] = 0;
    __syncthreads();
    int start = blockIdx.x * epb;
    int end   = min(E, start + epb);
    for (int e = start + threadIdx.x; e < end; e += 256)
        atomicAdd(&h[rows[e] >> BKT_SH], 1);
    __syncthreads();
    for (int i = threadIdx.x; i < NBKT; i += 256)
        if (h[i]) atomicAdd(&bkt_total[i], h[i]);
}

// ---------------- pass 2: single-block exclusive scan over buckets ----------------
__global__ __launch_bounds__(1024) void bkt_scan(const int* __restrict__ bkt_total,
                                                 int* __restrict__ bktstart,
                                                 int* __restrict__ cursor,
                                                 int* __restrict__ rp, int E) {
    __shared__ int s[1024];
    __shared__ int carry;
    int t = threadIdx.x;
    if (t == 0) { carry = 0; bktstart[NBKT] = E; rp[NN] = E; }
    __syncthreads();
    for (int base = 0; base < NBKT; base += 1024) {
        int i = base + t;
        int v = (i < NBKT) ? bkt_total[i] : 0;
        s[t] = v;
        __syncthreads();
        #pragma unroll
        for (int d = 1; d < 1024; d <<= 1) {
            int a = (t >= d) ? s[t - d] : 0;
            __syncthreads();
            s[t] += a;
            __syncthreads();
        }
        if (i < NBKT) { int ex = carry + s[t] - v; bktstart[i] = ex; cursor[i] = ex; }
        __syncthreads();
        if (t == 0) carry += s[1023];
        __syncthreads();
    }
}

// ---------------- pass 3: scatter into bucket-ordered runs ----------------
__global__ __launch_bounds__(256) void scatter_l1(const int* __restrict__ rows,
                                                  const int* __restrict__ cols,
                                                  const float* __restrict__ vals,
                                                  int* __restrict__ cursor,
                                                  int2* __restrict__ packed,
                                                  int E, int epb) {
    __shared__ int h[NBKT];
    __shared__ int base[NBKT];
    for (int i = threadIdx.x; i < NBKT; i += 256) h[i] = 0;
    __syncthreads();
    int start = blockIdx.x * epb;
    int end   = min(E, start + epb);
    for (int e = start + threadIdx.x; e < end; e += 256)
        atomicAdd(&h[rows[e] >> BKT_SH], 1);
    __syncthreads();
    for (int i = threadIdx.x; i < NBKT; i += 256) {
        int c = h[i];
        base[i] = c ? atomicAdd(&cursor[i], c) : 0;
        h[i] = 0;
    }
    __syncthreads();
    for (int e = start + threadIdx.x; e < end; e += 256) {
        int r = rows[e];
        int b = r >> BKT_SH;
        int p = base[b] + atomicAdd(&h[b], 1);
        packed[p] = make_int2(cols[e] | ((r & (BKT_RW - 1)) << 18),
                              __float_as_int(vals[e]));
    }
}

// ---------------- pass 4: per-bucket in-place sort to exact CSR ----------------
__global__ __launch_bounds__(256) void sort_l2(const int* __restrict__ bktstart,
                                               int2* __restrict__ packed,
                                               int* __restrict__ rp) {
    __shared__ int2 sm[L2CAP];
    __shared__ int  cnt[BKT_RW];
    __shared__ int  cur[BKT_RW];
    int b = blockIdx.x;
    int s = bktstart[b];
    int e = bktstart[b + 1];
    int n = e - s;
    int t = threadIdx.x;
    if (t < BKT_RW) cnt[t] = 0;
    __syncthreads();
    for (int i = t; i < n; i += 256) {
        int2 v = packed[s + i];
        sm[i] = v;
        atomicAdd(&cnt[(v.x >> 18) & (BKT_RW - 1)], 1);
    }
    __syncthreads();
    #pragma unroll
    for (int d = 1; d < BKT_RW; d <<= 1) {
        int a = (t < BKT_RW && t >= d) ? cnt[t - d] : 0;
        __syncthreads();
        if (t < BKT_RW) cnt[t] += a;
        __syncthreads();
    }
    if (t < BKT_RW) {
        int ex = t ? cnt[t - 1] : 0;
        cur[t] = ex;
        int g = (b << BKT_SH) + t;
        if (g < NN) rp[g] = s + ex;
    }
    __syncthreads();
    for (int i = t; i < n; i += 256) {
        int2 v = sm[i];
        int  p = atomicAdd(&cur[(v.x >> 18) & (BKT_RW - 1)], 1);
        packed[s + p] = make_int2(v.x & 0x3FFFF, v.y);
    }
}

// ---------------- gather SpMM: one wave per row, lane = feature ----------------
__global__ __launch_bounds__(256) void spmm_csr(const int* __restrict__ rp,
                                                const int2* __restrict__ packed,
                                                const float* __restrict__ ein,
                                                float* __restrict__ eout, int n) {
    int wid  = (blockIdx.x * 256 + threadIdx.x) >> 6;
    int lane = threadIdx.x & 63;
    if (wid >= n) return;
    int start = rp[wid];
    int end   = rp[wid + 1];
    float acc = 0.f;
    for (int b0 = start; b0 < end; b0 += 64) {
        int cnt = end - b0; if (cnt > 64) cnt = 64;
        int2 ev = make_int2(0, 0);
        if (lane < cnt) ev = packed[b0 + lane];
        int k = 0;
        for (; k + 4 <= cnt; k += 4) {
            int   c0 = __shfl(ev.x, k),     c1 = __shfl(ev.x, k + 1);
            int   c2 = __shfl(ev.x, k + 2), c3 = __shfl(ev.x, k + 3);
            float v0 = __int_as_float(__shfl(ev.y, k));
            float v1 = __int_as_float(__shfl(ev.y, k + 1));
            float v2 = __int_as_float(__shfl(ev.y, k + 2));
            float v3 = __int_as_float(__shfl(ev.y, k + 3));
            float x0 = ein[c0 * D + lane];
            float x1 = ein[c1 * D + lane];
            float x2 = ein[c2 * D + lane];
            float x3 = ein[c3 * D + lane];
            acc += v0 * x0; acc += v1 * x1; acc += v2 * x2; acc += v3 * x3;
        }
        for (; k < cnt; ++k) {
            int   c = __shfl(ev.x, k);
            float vv = __int_as_float(__shfl(ev.y, k));
            acc += vv * ein[c * D + lane];
        }
    }
    eout[(size_t)wid * D + lane] = acc;
}

// ---------------- fallback scatter SpMM (atomic path) ----------------
__global__ __launch_bounds__(256) void spmm_scatter(const int* __restrict__ rows,
                                                    const int* __restrict__ cols,
                                                    const float* __restrict__ vals,
                                                    const float* __restrict__ ein,
                                                    float* __restrict__ eout, int E) {
    int gid  = blockIdx.x * blockDim.x + threadIdx.x;
    int wid  = gid >> 6;
    int lane = threadIdx.x & 63;
    int nw   = (gridDim.x * blockDim.x) >> 6;
    for (int e = wid; e < E; e += nw) {
        int   r = rows[e];
        int   c = cols[e];
        float v = vals[e];
        float x = ein[(size_t)c * D + lane];
        unsafeAtomicAdd(&eout[(size_t)r * D + lane], v * x);
    }
}

// ---------------- MFMA fused 2-layer residual MLP + LayerNorm, in-place ----------------
// One wave per 16-row tile. y = relu(x@W^T + b) + x twice, then LN.
// x enters MFMA as bf16 hi+lo split (error ~2^-17); W as single bf16.
// A-frag: row = lane&15, k = (lane>>4)*8 + j. C/D: col = lane&15 (feature),
// row = (lane>>4)*4 + reg (m89-verified). LN reduces across low-4 lane bits.
__global__ __launch_bounds__(256) void mlp_mfma(float* __restrict__ e,
                                                const float* __restrict__ Ws,
                                                const float* __restrict__ bs,
                                                const float* __restrict__ gamma,
                                                const float* __restrict__ beta) {
    __shared__ float xp[4][16][68];   // per-wave transpose buffer (wave-private)
    int t  = threadIdx.x;
    int wv = t >> 6;
    int fr = t & 15;          // lane & 15
    int fq = (t & 63) >> 4;   // lane >> 4

    // ---- W fragments (bf16), both layers, register-resident ----
    short8 wf[2][4][2];
    #pragma unroll
    for (int l = 0; l < 2; ++l)
        #pragma unroll
        for (int nt = 0; nt < 4; ++nt)
            #pragma unroll
            for (int kk = 0; kk < 2; ++kk) {
                const float* src = Ws + l * 4096 + (nt * 16 + fr) * 64 + kk * 32 + fq * 8;
                float4 a = *(const float4*)src;
                float4 b = *(const float4*)(src + 4);
                short8 w;
                w[0] = f32_to_bf16_rne(a.x); w[1] = f32_to_bf16_rne(a.y);
                w[2] = f32_to_bf16_rne(a.z); w[3] = f32_to_bf16_rne(a.w);
                w[4] = f32_to_bf16_rne(b.x); w[5] = f32_to_bf16_rne(b.y);
                w[6] = f32_to_bf16_rne(b.z); w[7] = f32_to_bf16_rne(b.w);
                wf[l][nt][kk] = w;
            }
    float bia0[4], bia1[4], gam[4], bet[4];
    #pragma unroll
    for (int nt = 0; nt < 4; ++nt) {
        bia0[nt] = bs[nt * 16 + fr];
        bia1[nt] = bs[64 + nt * 16 + fr];
        gam[nt]  = gamma[nt * 16 + fr];
        bet[nt]  = beta[nt * 16 + fr];
    }

    int wgid = blockIdx.x * 4 + wv;
    int nwv  = gridDim.x * 4;
    for (int tile = wgid; tile < NTILE; tile += nwv) {
        float* base = e + (size_t)tile * 16 * D;

        // A-frags of x: hi/lo bf16 split
        short8 xh[2], xl[2];
        #pragma unroll
        for (int kk = 0; kk < 2; ++kk) {
            const float* s = base + fr * D + kk * 32 + fq * 8;
            float4 a = *(const float4*)s;
            float4 b = *(const float4*)(s + 4);
            float v[8] = {a.x, a.y, a.z, a.w, b.x, b.y, b.z, b.w};
            #pragma unroll
            for (int j = 0; j < 8; ++j) {
                unsigned short h = f32_to_bf16_rne(v[j]);
                xh[kk][j] = h;
                xl[kk][j] = f32_to_bf16_rne(v[j] - bf16_bits_to_f32(h));
            }
        }
        // residual copy in C-layout
        float xr[4][4];
        #pragma unroll
        for (int nt = 0; nt < 4; ++nt)
            #pragma unroll
            for (int j = 0; j < 4; ++j)
                xr[nt][j] = base[(fq * 4 + j) * D + nt * 16 + fr];

        // ---- layer 1 ----
        f32x4 acc[4];
        #pragma unroll
        for (int nt = 0; nt < 4; ++nt) {
            acc[nt] = f32x4{bia0[nt], bia0[nt], bia0[nt], bia0[nt]};
            #pragma unroll
            for (int kk = 0; kk < 2; ++kk) {
                acc[nt] = __builtin_amdgcn_mfma_f32_16x16x32_bf16(xh[kk], wf[0][nt][kk], acc[nt], 0, 0, 0);
                acc[nt] = __builtin_amdgcn_mfma_f32_16x16x32_bf16(xl[kk], wf[0][nt][kk], acc[nt], 0, 0, 0);
            }
        }
        float y1[4][4];
        #pragma unroll
        for (int nt = 0; nt < 4; ++nt)
            #pragma unroll
            for (int j = 0; j < 4; ++j) {
                y1[nt][j] = fmaxf(acc[nt][j], 0.f) + xr[nt][j];
                xp[wv][fq * 4 + j][nt * 16 + fr] = y1[nt][j];  // wave-private LDS
            }

        // layer-2 A-frags from LDS (fragment relayout)
        #pragma unroll
        for (int kk = 0; kk < 2; ++kk) {
            const float* s = &xp[wv][fr][kk * 32 + fq * 8];
            float4 a = *(const float4*)s;
            float4 b = *(const float4*)(s + 4);
            float v[8] = {a.x, a.y, a.z, a.w, b.x, b.y, b.z, b.w};
            #pragma unroll
            for (int j = 0; j < 8; ++j) {
                unsigned short h = f32_to_bf16_rne(v[j]);
                xh[kk][j] = h;
                xl[kk][j] = f32_to_bf16_rne(v[j] - bf16_bits_to_f32(h));
            }
        }

        // ---- layer 2 ----
        #pragma unroll
        for (int nt = 0; nt < 4; ++nt) {
            acc[nt] = f32x4{bia1[nt], bia1[nt], bia1[nt], bia1[nt]};
            #pragma unroll
            for (int kk = 0; kk < 2; ++kk) {
                acc[nt] = __builtin_amdgcn_mfma_f32_16x16x32_bf16(xh[kk], wf[1][nt][kk], acc[nt], 0, 0, 0);
                acc[nt] = __builtin_amdgcn_mfma_f32_16x16x32_bf16(xl[kk], wf[1][nt][kk], acc[nt], 0, 0, 0);
            }
        }
        float y2[4][4];
        #pragma unroll
        for (int nt = 0; nt < 4; ++nt)
            #pragma unroll
            for (int j = 0; j < 4; ++j)
                y2[nt][j] = fmaxf(acc[nt][j], 0.f) + y1[nt][j];

        // ---- LayerNorm per row j (features across nt and the low-4 lane bits) ----
        float sm[4], sq[4];
        #pragma unroll
        for (int j = 0; j < 4; ++j) {
            float s0 = 0.f, q0 = 0.f;
            #pragma unroll
            for (int nt = 0; nt < 4; ++nt) { s0 += y2[nt][j]; q0 += y2[nt][j] * y2[nt][j]; }
            sm[j] = s0; sq[j] = q0;
        }
        #pragma unroll
        for (int off = 1; off < 16; off <<= 1) {
            #pragma unroll
            for (int j = 0; j < 4; ++j) {
                sm[j] += __shfl_xor(sm[j], off);
                sq[j] += __shfl_xor(sq[j], off);
            }
        }
        #pragma unroll
        for (int j = 0; j < 4; ++j) {
            float mu  = sm[j] * (1.f / 64.f);
            float var = sq[j] * (1.f / 64.f) - mu * mu;
            float rs  = rsqrtf(var + 1e-5f);
            #pragma unroll
            for (int nt = 0; nt < 4; ++nt)
                base[(fq * 4 + j) * D + nt * 16 + fr] =
                    (y2[nt][j] - mu) * rs * gam[nt] + bet[nt];
        }
    }
}

extern "C" void kernel_launch(void* const* d_in, const int* in_sizes, int n_in,
                              void* d_out, int out_size, void* d_ws, size_t ws_size,
                              hipStream_t stream) {
    const int*   rows  = (const int*)d_in[0];
    const int*   cols  = (const int*)d_in[1];
    const float* vals  = (const float*)d_in[2];
    const float* ini   = (const float*)d_in[3];
    const float* Ws    = (const float*)d_in[4];
    const float* bs    = (const float*)d_in[5];
    const float* gamma = (const float*)d_in[6];
    const float* beta  = (const float*)d_in[7];
    float* out = (float*)d_out;
    int E = in_sizes[0];

    size_t e1_b     = (size_t)NN * D * 4;
    size_t packed_b = ((size_t)E * 8 + 63) & ~(size_t)63;
    size_t rp_b     = (((size_t)NN + 1) * 4 + 63) & ~(size_t)63;
    size_t bs_b     = (((size_t)NBKT + 1) * 4 + 63) & ~(size_t)63;
    size_t need     = e1_b + packed_b + rp_b + 3 * bs_b;

    if (ws_size >= need) {
        char* w = (char*)d_ws;
        float* e1       = (float*)w;   w += e1_b;
        int2*  packed   = (int2*)w;    w += packed_b;
        int*   rp       = (int*)w;     w += rp_b;
        int*   bktstart = (int*)w;     w += bs_b;
        int*   bkt_tot  = (int*)w;     w += bs_b;
        int*   cursor   = (int*)w;

        int epb = (E + NCHUNK - 1) / NCHUNK;
        zero_i<<<(NBKT + 255) / 256, 256, 0, stream>>>(bkt_tot, NBKT);
        bkt_count<<<NCHUNK, 256, 0, stream>>>(rows, bkt_tot, E, epb);
        bkt_scan<<<1, 1024, 0, stream>>>(bkt_tot, bktstart, cursor, rp, E);
        scatter_l1<<<NCHUNK, 256, 0, stream>>>(rows, cols, vals, cursor, packed, E, epb);
        sort_l2<<<NBKT, 256, 0, stream>>>(bktstart, packed, rp);

        int spmm_blocks = (NN * 64 + 255) / 256;
        spmm_csr<<<spmm_blocks, 256, 0, stream>>>(rp, packed, ini, e1, NN);
        spmm_csr<<<spmm_blocks, 256, 0, stream>>>(rp, packed, e1, out, NN);
    } else {
        float* e1 = (float*)d_ws;
        int n4 = out_size / 4;
        int zb = (n4 + 255) / 256;
        zero_f4<<<zb, 256, 0, stream>>>((float4*)e1,  n4);
        zero_f4<<<zb, 256, 0, stream>>>((float4*)out, n4);
        spmm_scatter<<<12800, 256, 0, stream>>>(rows, cols, vals, ini, e1, E);
        spmm_scatter<<<12800, 256, 0, stream>>>(rows, cols, vals, e1, out, E);
    }

    mlp_mfma<<<1563, 256, 0, stream>>>(out, Ws, bs, gamma, beta);
}